// Round 1
// baseline (227.285 us; speedup 1.0000x reference)
//
#include <hip/hip_runtime.h>
#include <cstdint>
#include <cstddef>

#define BATCH 1024
#define SEQL  128
#define DIM   768
#define HID   256
#define KIN1  1536
#define BN_EPS 1e-5f

typedef unsigned short u16;
typedef __attribute__((ext_vector_type(8))) short short8;
typedef __attribute__((ext_vector_type(4))) float f32x4;

__device__ __forceinline__ u16 f2bf(float f) {
  uint32_t u = __float_as_uint(f);
  return (u16)((u + 0x7fffu + ((u >> 16) & 1u)) >> 16);  // RNE, finite inputs
}
__device__ __forceinline__ void add4(float4& a, const float4 v) {
  a.x += v.x; a.y += v.y; a.z += v.z; a.w += v.w;
}

// ---------------- 1. ragged mean pool: [B,L,D] f32 -> x_bf16 [B, 2D] ----------------
// grid (B, 2), block 192 (one float4 column per thread)
__global__ __launch_bounds__(192) void pool_kernel(
    const float* __restrict__ uf, const float* __restrict__ hf,
    const int* __restrict__ ul, const int* __restrict__ hl,
    u16* __restrict__ xb) {
  const int b = blockIdx.x;
  const int which = blockIdx.y;
  const float4* src = (const float4*)((which ? hf : uf) + (size_t)b * (SEQL * DIM));
  const int len = which ? hl[b] : ul[b];
  const int t = threadIdx.x;  // 0..191

  float4 a0 = make_float4(0.f, 0.f, 0.f, 0.f), a1 = a0, a2 = a0, a3 = a0;
  int l = 0;
  for (; l + 4 <= len; l += 4) {
    float4 v0 = src[(size_t)(l + 0) * 192 + t];
    float4 v1 = src[(size_t)(l + 1) * 192 + t];
    float4 v2 = src[(size_t)(l + 2) * 192 + t];
    float4 v3 = src[(size_t)(l + 3) * 192 + t];
    add4(a0, v0); add4(a1, v1); add4(a2, v2); add4(a3, v3);
  }
  for (; l < len; ++l) add4(a0, src[(size_t)l * 192 + t]);
  add4(a0, a1); add4(a2, a3); add4(a0, a2);
  const float s = 1.f / (float)len;
  ushort4 o = make_ushort4(f2bf(a0.x * s), f2bf(a0.y * s), f2bf(a0.z * s), f2bf(a0.w * s));
  *(ushort4*)(xb + (size_t)b * KIN1 + which * DIM + t * 4) = o;
}

// ---------------- 2. f32 -> bf16 convert (weights) ----------------
__global__ void cvt_bf16_kernel(const float* __restrict__ in, u16* __restrict__ out, int n4) {
  int i = blockIdx.x * blockDim.x + threadIdx.x;
  if (i >= n4) return;
  float4 v = ((const float4*)in)[i];
  ushort4 o = make_ushort4(f2bf(v.x), f2bf(v.y), f2bf(v.z), f2bf(v.w));
  ((ushort4*)out)[i] = o;
}

// ---------------- 3. GEMM: C[M,N] = A_bf16[M,K] * W_bf16[N,K]^T + bias ----------------
// BM=128, BN=64, BK=64; 256 threads = 4 waves (2x2), wave tile 64x32 (4x2 frags of 16x16)
#define GBM 128
#define GBN 64
#define GBK 64
#define LDT 72  // padded row stride in u16 (144 B = 9*16B -> 16B aligned, conflict-light)

__global__ __launch_bounds__(256) void gemm_bf16(
    const u16* __restrict__ A, const u16* __restrict__ W,
    const float* __restrict__ bias, float* __restrict__ C,
    int N, int K) {
  __shared__ u16 lA[GBM * LDT];
  __shared__ u16 lB[GBN * LDT];
  const int tid = threadIdx.x;
  const int lane = tid & 63;
  const int wv = tid >> 6;
  const int wr = wv >> 1, wc = wv & 1;
  const int r16 = lane & 15, kgrp = lane >> 4;
  const int bm = blockIdx.x, bn = blockIdx.y;
  const int sr = tid >> 3;  // staging row base (0..31)
  const int sc = tid & 7;   // staging 16B slot (0..7)

  f32x4 acc[4][2];
#pragma unroll
  for (int mi = 0; mi < 4; ++mi)
#pragma unroll
    for (int ni = 0; ni < 2; ++ni)
      acc[mi][ni] = (f32x4){0.f, 0.f, 0.f, 0.f};

  const u16* Abase = A + (size_t)bm * GBM * K;
  const u16* Wbase = W + (size_t)bn * GBN * K;

  for (int k0 = 0; k0 < K; k0 += GBK) {
    uint4 ra[4], rb[2];
#pragma unroll
    for (int s = 0; s < 4; ++s)
      ra[s] = *(const uint4*)(Abase + (size_t)(sr + s * 32) * K + k0 + sc * 8);
#pragma unroll
    for (int s = 0; s < 2; ++s)
      rb[s] = *(const uint4*)(Wbase + (size_t)(sr + s * 32) * K + k0 + sc * 8);
    __syncthreads();  // previous iter's ds_reads done
#pragma unroll
    for (int s = 0; s < 4; ++s)
      *(uint4*)(lA + (sr + s * 32) * LDT + sc * 8) = ra[s];
#pragma unroll
    for (int s = 0; s < 2; ++s)
      *(uint4*)(lB + (sr + s * 32) * LDT + sc * 8) = rb[s];
    __syncthreads();
#pragma unroll
    for (int kk = 0; kk < 2; ++kk) {
      const int koff = (kk * 4 + kgrp) * 8;
      short8 af[4], bfr[2];
#pragma unroll
      for (int mi = 0; mi < 4; ++mi)
        af[mi] = *(const short8*)(lA + (wr * 64 + mi * 16 + r16) * LDT + koff);
#pragma unroll
      for (int ni = 0; ni < 2; ++ni)
        bfr[ni] = *(const short8*)(lB + (wc * 32 + ni * 16 + r16) * LDT + koff);
#pragma unroll
      for (int mi = 0; mi < 4; ++mi)
#pragma unroll
        for (int ni = 0; ni < 2; ++ni)
          acc[mi][ni] = __builtin_amdgcn_mfma_f32_16x16x32_bf16(af[mi], bfr[ni], acc[mi][ni], 0, 0, 0);
    }
  }
  __syncthreads();
#pragma unroll
  for (int mi = 0; mi < 4; ++mi) {
#pragma unroll
    for (int ni = 0; ni < 2; ++ni) {
      const int col = bn * GBN + wc * 32 + ni * 16 + r16;
      const float bv = bias[col];
#pragma unroll
      for (int rg = 0; rg < 4; ++rg) {
        const int row = bm * GBM + wr * 64 + mi * 16 + kgrp * 4 + rg;
        C[(size_t)row * N + col] = acc[mi][ni][rg] + bv;
      }
    }
  }
}

// ---------------- 4. BN stats: per-column mean & rstd over B rows ----------------
// grid N/64, block 1024 (16 row-groups x 64 cols)
__global__ __launch_bounds__(1024) void bn_stats_kernel(
    const float* __restrict__ y, float* __restrict__ mean, float* __restrict__ rstd, int N) {
  __shared__ float sh[2][16][64];
  const int t = threadIdx.x;
  const int c = (blockIdx.x << 6) + (t & 63);
  const int rg = t >> 6;  // 0..15
  float s = 0.f, s2 = 0.f;
  for (int r = rg; r < BATCH; r += 16) {
    float v = y[(size_t)r * N + c];
    s += v; s2 += v * v;
  }
  sh[0][rg][t & 63] = s;
  sh[1][rg][t & 63] = s2;
  __syncthreads();
  if (t < 64) {
    float ss = 0.f, ss2 = 0.f;
#pragma unroll
    for (int g = 0; g < 16; ++g) { ss += sh[0][g][t]; ss2 += sh[1][g][t]; }
    float m = ss * (1.f / BATCH);
    float var = ss2 * (1.f / BATCH) - m * m;
    mean[(blockIdx.x << 6) + t] = m;
    rstd[(blockIdx.x << 6) + t] = rsqrtf(var + BN_EPS);
  }
}

// ---------------- 5. BN apply + ReLU (+ optional bf16 cast) ----------------
template <int BF16OUT>
__global__ __launch_bounds__(256) void bn_apply_kernel(
    const float* __restrict__ y, const float* __restrict__ mean, const float* __restrict__ rstd,
    const float* __restrict__ gam, const float* __restrict__ bet,
    void* __restrict__ out, int N) {
  const int i = blockIdx.x * blockDim.x + threadIdx.x;  // float4 index
  const int n4 = (BATCH * N) >> 2;
  if (i >= n4) return;
  float4 v = ((const float4*)y)[i];
  const int c = (i << 2) % N;
  float o0 = fmaxf(0.f, (v.x - mean[c + 0]) * rstd[c + 0] * gam[c + 0] + bet[c + 0]);
  float o1 = fmaxf(0.f, (v.y - mean[c + 1]) * rstd[c + 1] * gam[c + 1] + bet[c + 1]);
  float o2 = fmaxf(0.f, (v.z - mean[c + 2]) * rstd[c + 2] * gam[c + 2] + bet[c + 2]);
  float o3 = fmaxf(0.f, (v.w - mean[c + 3]) * rstd[c + 3] * gam[c + 3] + bet[c + 3]);
  if (BF16OUT) {
    ushort4 o = make_ushort4(f2bf(o0), f2bf(o1), f2bf(o2), f2bf(o3));
    ((ushort4*)out)[i] = o;
  } else {
    ((float4*)out)[i] = make_float4(o0, o1, o2, o3);
  }
}

// ---------------- 6. fc3 dot + sigmoid ----------------
// one wave per row; block 256 = 4 rows
__global__ __launch_bounds__(256) void fc3_kernel(
    const float* __restrict__ x2, const float* __restrict__ w,
    const float* __restrict__ b3, float* __restrict__ out) {
  const int row = (blockIdx.x * 256 + threadIdx.x) >> 6;
  const int lane = threadIdx.x & 63;
  float4 xv = ((const float4*)(x2 + (size_t)row * HID))[lane];
  float4 wv = ((const float4*)w)[lane];
  float d = xv.x * wv.x + xv.y * wv.y + xv.z * wv.z + xv.w * wv.w;
#pragma unroll
  for (int off = 32; off > 0; off >>= 1) d += __shfl_down(d, off, 64);
  if (lane == 0) out[row] = 1.f / (1.f + expf(-(d + b3[0])));
}

// ---------------- launch ----------------
extern "C" void kernel_launch(void* const* d_in, const int* in_sizes, int n_in,
                              void* d_out, int out_size, void* d_ws, size_t ws_size,
                              hipStream_t stream) {
  const float* uf   = (const float*)d_in[0];
  const float* hf   = (const float*)d_in[1];
  const int*   ul   = (const int*)d_in[2];
  const int*   hl   = (const int*)d_in[3];
  const float* fc1w = (const float*)d_in[4];
  const float* fc1b = (const float*)d_in[5];
  const float* bn1g = (const float*)d_in[6];
  const float* bn1b = (const float*)d_in[7];
  const float* fc2w = (const float*)d_in[8];
  const float* fc2b = (const float*)d_in[9];
  const float* bn2g = (const float*)d_in[10];
  const float* bn2b = (const float*)d_in[11];
  const float* fc3w = (const float*)d_in[12];
  const float* fc3b = (const float*)d_in[13];
  float* out = (float*)d_out;

  char* ws = (char*)d_ws;
  u16*   xb  = (u16*)  (ws + 0);         // 1024*1536 bf16
  u16*   w1b = (u16*)  (ws + 3145728);   // 768*1536 bf16
  u16*   w2b = (u16*)  (ws + 5505024);   // 256*768 bf16
  float* y1  = (float*)(ws + 5898240);   // 1024*768 f32
  u16*   x1b = (u16*)  (ws + 9043968);   // 1024*768 bf16
  float* y2  = (float*)(ws + 10616832);  // 1024*256 f32
  float* x2f = (float*)(ws + 11665408);  // 1024*256 f32
  float* m1  = (float*)(ws + 12713984);
  float* r1  = m1 + DIM;
  float* m2  = r1 + DIM;
  float* r2  = m2 + HID;

  pool_kernel<<<dim3(BATCH, 2), 192, 0, stream>>>(uf, hf, ul, hl, xb);
  cvt_bf16_kernel<<<(DIM * KIN1 / 4 + 255) / 256, 256, 0, stream>>>(fc1w, w1b, DIM * KIN1 / 4);
  cvt_bf16_kernel<<<(HID * DIM / 4 + 255) / 256, 256, 0, stream>>>(fc2w, w2b, HID * DIM / 4);

  gemm_bf16<<<dim3(BATCH / GBM, DIM / GBN), 256, 0, stream>>>(xb, w1b, fc1b, y1, DIM, KIN1);
  bn_stats_kernel<<<DIM / 64, 1024, 0, stream>>>(y1, m1, r1, DIM);
  bn_apply_kernel<1><<<(BATCH * DIM / 4) / 256, 256, 0, stream>>>(y1, m1, r1, bn1g, bn1b, (void*)x1b, DIM);

  gemm_bf16<<<dim3(BATCH / GBM, HID / GBN), 256, 0, stream>>>(x1b, w2b, fc2b, y2, HID, DIM);
  bn_stats_kernel<<<HID / 64, 1024, 0, stream>>>(y2, m2, r2, HID);
  bn_apply_kernel<0><<<(BATCH * HID / 4) / 256, 256, 0, stream>>>(y2, m2, r2, bn2g, bn2b, (void*)x2f, HID);

  fc3_kernel<<<BATCH / 4, 256, 0, stream>>>(x2f, fc3w, fc3b, out);
}

// Round 2
// 118.482 us; speedup vs baseline: 1.9183x; 1.9183x over previous
//
#include <hip/hip_runtime.h>
#include <cstdint>
#include <cstddef>

#define BATCH 1024
#define SEQL  128
#define DIM   768
#define HID   256
#define KIN1  1536
#define BN_EPS 1e-5f

typedef unsigned short u16;
typedef __attribute__((ext_vector_type(8))) short short8;
typedef __attribute__((ext_vector_type(4))) float f32x4;

__device__ __forceinline__ u16 f2bf(float f) {
  uint32_t u = __float_as_uint(f);
  return (u16)((u + 0x7fffu + ((u >> 16) & 1u)) >> 16);  // RNE, finite inputs
}
__device__ __forceinline__ f32x4 ntl(const f32x4* p) { return __builtin_nontemporal_load(p); }
__device__ __forceinline__ float kred(float v) {  // reduce over kgrp lanes (lane bits 4,5)
  v += __shfl_xor(v, 16);
  v += __shfl_xor(v, 32);
  return v;
}

// ---------------- 1. ragged mean pool: [B,L,D] f32 -> x_bf16 [B, 2D] ----------------
// grid (B, 2), block 192 (one float4 column per thread)
__global__ __launch_bounds__(192) void pool_kernel(
    const float* __restrict__ uf, const float* __restrict__ hf,
    const int* __restrict__ ul, const int* __restrict__ hl,
    u16* __restrict__ xb) {
  const int b = blockIdx.x;
  const int which = blockIdx.y;
  const f32x4* src = (const f32x4*)((which ? hf : uf) + (size_t)b * (SEQL * DIM));
  const int len = which ? hl[b] : ul[b];
  const int t = threadIdx.x;  // 0..191

  f32x4 a0 = (f32x4){0.f, 0.f, 0.f, 0.f}, a1 = a0, a2 = a0, a3 = a0;
  int l = 0;
  for (; l + 8 <= len; l += 8) {
    f32x4 v0 = ntl(src + (size_t)(l + 0) * 192 + t);
    f32x4 v1 = ntl(src + (size_t)(l + 1) * 192 + t);
    f32x4 v2 = ntl(src + (size_t)(l + 2) * 192 + t);
    f32x4 v3 = ntl(src + (size_t)(l + 3) * 192 + t);
    f32x4 v4 = ntl(src + (size_t)(l + 4) * 192 + t);
    f32x4 v5 = ntl(src + (size_t)(l + 5) * 192 + t);
    f32x4 v6 = ntl(src + (size_t)(l + 6) * 192 + t);
    f32x4 v7 = ntl(src + (size_t)(l + 7) * 192 + t);
    a0 += v0; a1 += v1; a2 += v2; a3 += v3;
    a0 += v4; a1 += v5; a2 += v6; a3 += v7;
  }
  for (; l < len; ++l) a0 += ntl(src + (size_t)l * 192 + t);
  a0 += a1; a2 += a3; a0 += a2;
  const float s = 1.f / (float)len;
  ushort4 o = make_ushort4(f2bf(a0[0] * s), f2bf(a0[1] * s), f2bf(a0[2] * s), f2bf(a0[3] * s));
  *(ushort4*)(xb + (size_t)b * KIN1 + which * DIM + t * 4) = o;
}

// ---------------- 2. prep: convert both weight matrices to bf16 ----------------
__global__ __launch_bounds__(256) void prep_kernel(
    const float* __restrict__ w1, const float* __restrict__ w2,
    u16* __restrict__ w1b, u16* __restrict__ w2b) {
  const int n1 = DIM * KIN1 / 4;   // 294912
  const int n2 = HID * DIM / 4;    // 49152
  int i = blockIdx.x * 256 + threadIdx.x;
  if (i < n1) {
    f32x4 v = ((const f32x4*)w1)[i];
    ((ushort4*)w1b)[i] = make_ushort4(f2bf(v[0]), f2bf(v[1]), f2bf(v[2]), f2bf(v[3]));
  } else {
    i -= n1;
    if (i < n2) {
      f32x4 v = ((const f32x4*)w2)[i];
      ((ushort4*)w2b)[i] = make_ushort4(f2bf(v[0]), f2bf(v[1]), f2bf(v[2]), f2bf(v[3]));
    }
  }
}

// ---------------- 3. gemm1: y1[1024,768] = xb[1024,1536] @ w1b^T + b1; + column partials ----------------
// BM=64, BN=64, BK=64; 256 thr = 4 waves (2x2), wave tile 32x32 (2x2 frags)
#define LDT 72  // padded row stride in u16

__global__ __launch_bounds__(256) void gemm1_kernel(
    const u16* __restrict__ A, const u16* __restrict__ W,
    const float* __restrict__ bias, float* __restrict__ y, float* __restrict__ p1) {
  __shared__ u16 lA[64 * LDT];
  __shared__ u16 lB[64 * LDT];
  __shared__ float red[2][64][2];
  const int K = KIN1, N = DIM;
  const int tid = threadIdx.x, lane = tid & 63, wv = tid >> 6;
  const int wr = wv >> 1, wc = wv & 1;
  const int r16 = lane & 15, kgrp = lane >> 4;
  const int bm = blockIdx.x, bn = blockIdx.y;
  const int sr = tid >> 3, sc8 = (tid & 7) * 8;

  f32x4 acc[2][2];
#pragma unroll
  for (int mi = 0; mi < 2; ++mi)
#pragma unroll
    for (int ni = 0; ni < 2; ++ni) acc[mi][ni] = (f32x4){0.f, 0.f, 0.f, 0.f};

  const u16* Ab = A + (size_t)bm * 64 * K;
  const u16* Wb = W + (size_t)bn * 64 * K;

  for (int k0 = 0; k0 < K; k0 += 64) {
    uint4 ra0 = *(const uint4*)(Ab + (size_t)sr * K + k0 + sc8);
    uint4 ra1 = *(const uint4*)(Ab + (size_t)(sr + 32) * K + k0 + sc8);
    uint4 rb0 = *(const uint4*)(Wb + (size_t)sr * K + k0 + sc8);
    uint4 rb1 = *(const uint4*)(Wb + (size_t)(sr + 32) * K + k0 + sc8);
    __syncthreads();
    *(uint4*)(lA + sr * LDT + sc8) = ra0;
    *(uint4*)(lA + (sr + 32) * LDT + sc8) = ra1;
    *(uint4*)(lB + sr * LDT + sc8) = rb0;
    *(uint4*)(lB + (sr + 32) * LDT + sc8) = rb1;
    __syncthreads();
#pragma unroll
    for (int kk = 0; kk < 2; ++kk) {
      const int koff = (kk * 4 + kgrp) * 8;
      short8 af0 = *(const short8*)(lA + (wr * 32 + r16) * LDT + koff);
      short8 af1 = *(const short8*)(lA + (wr * 32 + 16 + r16) * LDT + koff);
      short8 bf0 = *(const short8*)(lB + (wc * 32 + r16) * LDT + koff);
      short8 bf1 = *(const short8*)(lB + (wc * 32 + 16 + r16) * LDT + koff);
      acc[0][0] = __builtin_amdgcn_mfma_f32_16x16x32_bf16(af0, bf0, acc[0][0], 0, 0, 0);
      acc[0][1] = __builtin_amdgcn_mfma_f32_16x16x32_bf16(af0, bf1, acc[0][1], 0, 0, 0);
      acc[1][0] = __builtin_amdgcn_mfma_f32_16x16x32_bf16(af1, bf0, acc[1][0], 0, 0, 0);
      acc[1][1] = __builtin_amdgcn_mfma_f32_16x16x32_bf16(af1, bf1, acc[1][1], 0, 0, 0);
    }
  }

  // epilogue: write y (+bias) and per-block column partial sum/sumsq
#pragma unroll
  for (int ni = 0; ni < 2; ++ni) {
    const int col = bn * 64 + wc * 32 + ni * 16 + r16;
    const float bv = bias[col];
    float s = 0.f, s2 = 0.f;
#pragma unroll
    for (int mi = 0; mi < 2; ++mi)
#pragma unroll
      for (int rg = 0; rg < 4; ++rg) {
        const int row = bm * 64 + wr * 32 + mi * 16 + kgrp * 4 + rg;
        const float v = acc[mi][ni][rg] + bv;
        y[(size_t)row * N + col] = v;
        s += v; s2 += v * v;
      }
    s = kred(s); s2 = kred(s2);
    if (lane < 16) {
      red[wr][wc * 32 + ni * 16 + r16][0] = s;
      red[wr][wc * 32 + ni * 16 + r16][1] = s2;
    }
  }
  __syncthreads();
  if (tid < 128) {
    const int col = tid >> 1, wh = tid & 1;
    p1[((size_t)bm * DIM + bn * 64 + col) * 2 + wh] = red[0][col][wh] + red[1][col][wh];
  }
}

// ---------------- 4. gemm2: y2[1024,256] = relu(bn1(y1)) @ w2b^T + b2; + column partials ----------------
// BM=64, BN=32; 4 waves (2x2), wave tile 32x16 (2x1 frags). BN1 applied during A-staging.
__global__ __launch_bounds__(256) void gemm2_kernel(
    const float* __restrict__ y1, const u16* __restrict__ W,
    const float* __restrict__ bias, const float* __restrict__ g, const float* __restrict__ be,
    const float* __restrict__ p1, float* __restrict__ y2, float* __restrict__ p2) {
  __shared__ u16 lA[64 * LDT];
  __shared__ u16 lB[32 * LDT];
  __shared__ float sS[DIM], sH[DIM];
  __shared__ float red[2][32][2];
  const int K = DIM, N = HID;
  const int tid = threadIdx.x, lane = tid & 63, wv = tid >> 6;
  const int wr = wv >> 1, wc = wv & 1;
  const int r16 = lane & 15, kgrp = lane >> 4;
  const int bm = blockIdx.x, bn = blockIdx.y;
  const int sr = tid >> 3, sc8 = (tid & 7) * 8;

  // prologue: fold partials -> BN1 scale/shift (deterministic fixed-order sum)
  for (int c = tid; c < DIM; c += 256) {
    float s = 0.f, s2 = 0.f;
#pragma unroll
    for (int i = 0; i < 16; ++i) {
      float2 pv = *(const float2*)(p1 + ((size_t)i * DIM + c) * 2);
      s += pv.x; s2 += pv.y;
    }
    const float m = s * (1.f / BATCH);
    const float var = s2 * (1.f / BATCH) - m * m;
    const float r = rsqrtf(var + BN_EPS);
    const float scl = r * g[c];
    sS[c] = scl;
    sH[c] = be[c] - m * scl;
  }
  __syncthreads();

  f32x4 acc[2];
  acc[0] = (f32x4){0.f, 0.f, 0.f, 0.f};
  acc[1] = acc[0];

  const float* Ab = y1 + (size_t)bm * 64 * K;
  const u16* Wb = W + (size_t)bn * 32 * K;

  for (int k0 = 0; k0 < K; k0 += 64) {
    f32x4 va00 = *(const f32x4*)(Ab + (size_t)sr * K + k0 + sc8);
    f32x4 va01 = *(const f32x4*)(Ab + (size_t)sr * K + k0 + sc8 + 4);
    f32x4 va10 = *(const f32x4*)(Ab + (size_t)(sr + 32) * K + k0 + sc8);
    f32x4 va11 = *(const f32x4*)(Ab + (size_t)(sr + 32) * K + k0 + sc8 + 4);
    uint4 rb = *(const uint4*)(Wb + (size_t)sr * K + k0 + sc8);
    f32x4 s0 = *(const f32x4*)&sS[k0 + sc8];
    f32x4 s1 = *(const f32x4*)&sS[k0 + sc8 + 4];
    f32x4 h0 = *(const f32x4*)&sH[k0 + sc8];
    f32x4 h1 = *(const f32x4*)&sH[k0 + sc8 + 4];
    __syncthreads();
    union { ushort us[8]; uint4 q; } pk0, pk1;
#pragma unroll
    for (int j = 0; j < 4; ++j) {
      pk0.us[j]     = f2bf(fmaxf(0.f, va00[j] * s0[j] + h0[j]));
      pk0.us[4 + j] = f2bf(fmaxf(0.f, va01[j] * s1[j] + h1[j]));
      pk1.us[j]     = f2bf(fmaxf(0.f, va10[j] * s0[j] + h0[j]));
      pk1.us[4 + j] = f2bf(fmaxf(0.f, va11[j] * s1[j] + h1[j]));
    }
    *(uint4*)(lA + sr * LDT + sc8) = pk0.q;
    *(uint4*)(lA + (sr + 32) * LDT + sc8) = pk1.q;
    *(uint4*)(lB + sr * LDT + sc8) = rb;
    __syncthreads();
#pragma unroll
    for (int kk = 0; kk < 2; ++kk) {
      const int koff = (kk * 4 + kgrp) * 8;
      short8 af0 = *(const short8*)(lA + (wr * 32 + r16) * LDT + koff);
      short8 af1 = *(const short8*)(lA + (wr * 32 + 16 + r16) * LDT + koff);
      short8 bf0 = *(const short8*)(lB + (wc * 16 + r16) * LDT + koff);
      acc[0] = __builtin_amdgcn_mfma_f32_16x16x32_bf16(af0, bf0, acc[0], 0, 0, 0);
      acc[1] = __builtin_amdgcn_mfma_f32_16x16x32_bf16(af1, bf0, acc[1], 0, 0, 0);
    }
  }

  // epilogue
  {
    const int col = bn * 32 + wc * 16 + r16;
    const float bv = bias[col];
    float s = 0.f, s2 = 0.f;
#pragma unroll
    for (int mi = 0; mi < 2; ++mi)
#pragma unroll
      for (int rg = 0; rg < 4; ++rg) {
        const int row = bm * 64 + wr * 32 + mi * 16 + kgrp * 4 + rg;
        const float v = acc[mi][rg] + bv;
        y2[(size_t)row * N + col] = v;
        s += v; s2 += v * v;
      }
    s = kred(s); s2 = kred(s2);
    if (lane < 16) {
      red[wr][wc * 16 + r16][0] = s;
      red[wr][wc * 16 + r16][1] = s2;
    }
  }
  __syncthreads();
  if (tid < 64) {
    const int col = tid >> 1, wh = tid & 1;
    p2[((size_t)bm * HID + bn * 32 + col) * 2 + wh] = red[0][col][wh] + red[1][col][wh];
  }
}

// ---------------- 5. fc3: out = sigmoid(relu(bn2(y2)) @ w3^T + b3) ----------------
// grid 256 blocks x 256 thr; prologue folds p2 -> BN2 scale/shift; wave per row (4 rows/block)
__global__ __launch_bounds__(256) void fc3_kernel(
    const float* __restrict__ y2, const float* __restrict__ p2,
    const float* __restrict__ g, const float* __restrict__ be,
    const float* __restrict__ w3, const float* __restrict__ b3, float* __restrict__ out) {
  __shared__ float sS[HID], sH[HID];
  const int tid = threadIdx.x;
  {
    const int c = tid;  // 256 threads = 256 cols
    float s = 0.f, s2 = 0.f;
#pragma unroll
    for (int i = 0; i < 16; ++i) {
      float2 pv = *(const float2*)(p2 + ((size_t)i * HID + c) * 2);
      s += pv.x; s2 += pv.y;
    }
    const float m = s * (1.f / BATCH);
    const float var = s2 * (1.f / BATCH) - m * m;
    const float r = rsqrtf(var + BN_EPS);
    const float scl = r * g[c];
    sS[c] = scl;
    sH[c] = be[c] - m * scl;
  }
  __syncthreads();
  const int row = blockIdx.x * 4 + (tid >> 6);
  const int lane = tid & 63;
  f32x4 xv = *(const f32x4*)(y2 + (size_t)row * HID + lane * 4);
  f32x4 sc = *(const f32x4*)&sS[lane * 4];
  f32x4 sh = *(const f32x4*)&sH[lane * 4];
  f32x4 wv = *(const f32x4*)(w3 + lane * 4);
  float d = 0.f;
#pragma unroll
  for (int j = 0; j < 4; ++j) d += fmaxf(0.f, xv[j] * sc[j] + sh[j]) * wv[j];
#pragma unroll
  for (int off = 32; off > 0; off >>= 1) d += __shfl_xor(d, off);
  if (lane == 0) out[row] = 1.f / (1.f + expf(-(d + b3[0])));
}

// ---------------- launch ----------------
extern "C" void kernel_launch(void* const* d_in, const int* in_sizes, int n_in,
                              void* d_out, int out_size, void* d_ws, size_t ws_size,
                              hipStream_t stream) {
  const float* uf   = (const float*)d_in[0];
  const float* hf   = (const float*)d_in[1];
  const int*   ul   = (const int*)d_in[2];
  const int*   hl   = (const int*)d_in[3];
  const float* fc1w = (const float*)d_in[4];
  const float* fc1b = (const float*)d_in[5];
  const float* bn1g = (const float*)d_in[6];
  const float* bn1b = (const float*)d_in[7];
  const float* fc2w = (const float*)d_in[8];
  const float* fc2b = (const float*)d_in[9];
  const float* bn2g = (const float*)d_in[10];
  const float* bn2b = (const float*)d_in[11];
  const float* fc3w = (const float*)d_in[12];
  const float* fc3b = (const float*)d_in[13];
  float* out = (float*)d_out;

  char* ws = (char*)d_ws;
  u16*   xb  = (u16*)  (ws + 0);          // 1024*1536 bf16  (3145728 B)
  u16*   w1b = (u16*)  (ws + 3145728);    // 768*1536 bf16   (2359296 B)
  u16*   w2b = (u16*)  (ws + 5505024);    // 256*768 bf16    (393216 B)
  float* y1  = (float*)(ws + 5898240);    // 1024*768 f32    (3145728 B)
  float* y2  = (float*)(ws + 9043968);    // 1024*256 f32    (1048576 B)
  float* p1  = (float*)(ws + 10092544);   // 16*768*2 f32    (98304 B)
  float* p2  = (float*)(ws + 10190848);   // 16*256*2 f32    (32768 B)

  pool_kernel<<<dim3(BATCH, 2), 192, 0, stream>>>(uf, hf, ul, hl, xb);
  prep_kernel<<<1344, 256, 0, stream>>>(fc1w, fc2w, w1b, w2b);
  gemm1_kernel<<<dim3(16, 12), 256, 0, stream>>>(xb, w1b, fc1b, y1, p1);
  gemm2_kernel<<<dim3(16, 8), 256, 0, stream>>>(y1, w2b, fc2b, bn1g, bn1b, p1, y2, p2);
  fc3_kernel<<<256, 256, 0, stream>>>(y2, p2, bn2g, bn2b, fc3w, fc3b, out);
}

// Round 3
// 112.525 us; speedup vs baseline: 2.0199x; 1.0529x over previous
//
#include <hip/hip_runtime.h>
#include <cstdint>
#include <cstddef>

#define BATCH 1024
#define SEQL  128
#define DIM   768
#define HID   256
#define KIN1  1536
#define BN_EPS 1e-5f

typedef unsigned short u16;
typedef __attribute__((ext_vector_type(8))) short short8;
typedef __attribute__((ext_vector_type(4))) float f32x4;

__device__ __forceinline__ u16 f2bf(float f) {
  uint32_t u = __float_as_uint(f);
  return (u16)((u + 0x7fffu + ((u >> 16) & 1u)) >> 16);  // RNE, finite inputs
}
__device__ __forceinline__ f32x4 ntl(const f32x4* p) { return __builtin_nontemporal_load(p); }
__device__ __forceinline__ float kred(float v) {  // reduce over kgrp lanes (lane bits 4,5)
  v += __shfl_xor(v, 16);
  v += __shfl_xor(v, 32);
  return v;
}

// ---------------- 1. pool + weight-prep fused ----------------
// blocks 0..2047: ragged mean pool (b = id>>1, which = id&1)
// blocks 2048..2271: f32->bf16 weight conversion (rides free under pool's BW)
#define PREP_BLK 224
#define NW1Q (DIM * KIN1 / 4)   // 294912 float4s
#define NWQ  (NW1Q + HID * DIM / 4)  // 344064

__global__ __launch_bounds__(192) void pool_prep_kernel(
    const float* __restrict__ uf, const float* __restrict__ hf,
    const int* __restrict__ ul, const int* __restrict__ hl,
    const float* __restrict__ w1, const float* __restrict__ w2,
    u16* __restrict__ xb, u16* __restrict__ w1b, u16* __restrict__ w2b) {
  const int id = blockIdx.x;
  const int t = threadIdx.x;  // 0..191
  if (id < 2048) {
    const int b = id >> 1;
    const int which = id & 1;
    const f32x4* src = (const f32x4*)((which ? hf : uf) + (size_t)b * (SEQL * DIM));
    const int len = which ? hl[b] : ul[b];
    f32x4 a0 = (f32x4){0.f, 0.f, 0.f, 0.f}, a1 = a0, a2 = a0, a3 = a0;
    int l = 0;
    for (; l + 8 <= len; l += 8) {
      f32x4 v0 = ntl(src + (size_t)(l + 0) * 192 + t);
      f32x4 v1 = ntl(src + (size_t)(l + 1) * 192 + t);
      f32x4 v2 = ntl(src + (size_t)(l + 2) * 192 + t);
      f32x4 v3 = ntl(src + (size_t)(l + 3) * 192 + t);
      f32x4 v4 = ntl(src + (size_t)(l + 4) * 192 + t);
      f32x4 v5 = ntl(src + (size_t)(l + 5) * 192 + t);
      f32x4 v6 = ntl(src + (size_t)(l + 6) * 192 + t);
      f32x4 v7 = ntl(src + (size_t)(l + 7) * 192 + t);
      a0 += v0; a1 += v1; a2 += v2; a3 += v3;
      a0 += v4; a1 += v5; a2 += v6; a3 += v7;
    }
    for (; l < len; ++l) a0 += ntl(src + (size_t)l * 192 + t);
    a0 += a1; a2 += a3; a0 += a2;
    const float s = 1.f / (float)len;
    ushort4 o = make_ushort4(f2bf(a0[0] * s), f2bf(a0[1] * s), f2bf(a0[2] * s), f2bf(a0[3] * s));
    *(ushort4*)(xb + (size_t)b * KIN1 + which * DIM + t * 4) = o;
  } else {
    const int j = id - 2048;
    const int base = j * 192 + t;  // stride PREP_BLK*192 = 43008
#pragma unroll
    for (int s = 0; s < 8; ++s) {
      const int i = base + s * (PREP_BLK * 192);
      if (i < NW1Q) {
        f32x4 v = ((const f32x4*)w1)[i];
        ((ushort4*)w1b)[i] = make_ushort4(f2bf(v[0]), f2bf(v[1]), f2bf(v[2]), f2bf(v[3]));
      } else {
        const int i2 = i - NW1Q;
        f32x4 v = ((const f32x4*)w2)[i2];
        ((ushort4*)w2b)[i2] = make_ushort4(f2bf(v[0]), f2bf(v[1]), f2bf(v[2]), f2bf(v[3]));
      }
    }
  }
}

// ---------------- 2. gemm1: y1 = xb @ w1b^T + b1; + column partials ----------------
// BM=64, BN=64, BK=64; 256 thr = 4 waves (2x2), wave tile 32x32 (2x2 frags)
// double-buffered LDS, one barrier/iter; XCD chunk swizzle (4bm x 6bn per XCD)
#define LDT 72  // padded row stride in u16

__global__ __launch_bounds__(256) void gemm1_kernel(
    const u16* __restrict__ A, const u16* __restrict__ W,
    const float* __restrict__ bias, float* __restrict__ y, float* __restrict__ p1) {
  __shared__ u16 lA[2][64 * LDT];
  __shared__ u16 lB[2][64 * LDT];
  __shared__ float red[2][64][2];
  const int K = KIN1, N = DIM;
  const int tid = threadIdx.x, lane = tid & 63, wv = tid >> 6;
  const int wr = wv >> 1, wc = wv & 1;
  const int r16 = lane & 15, kgrp = lane >> 4;
  const int d = blockIdx.x;
  const int g = d & 7, j = d >> 3;
  const int bm = (g >> 1) * 4 + (j & 3);   // 0..15
  const int bn = (g & 1) * 6 + (j >> 2);   // 0..11
  const int sr = tid >> 3, sc8 = (tid & 7) * 8;

  f32x4 acc[2][2];
#pragma unroll
  for (int mi = 0; mi < 2; ++mi)
#pragma unroll
    for (int ni = 0; ni < 2; ++ni) acc[mi][ni] = (f32x4){0.f, 0.f, 0.f, 0.f};

  const u16* Ab = A + (size_t)bm * 64 * K;
  const u16* Wb = W + (size_t)bn * 64 * K;

  uint4 ra0, ra1, rb0, rb1;
#define G1_LOAD(k0)                                              \
  ra0 = *(const uint4*)(Ab + (size_t)sr * K + (k0) + sc8);       \
  ra1 = *(const uint4*)(Ab + (size_t)(sr + 32) * K + (k0) + sc8);\
  rb0 = *(const uint4*)(Wb + (size_t)sr * K + (k0) + sc8);       \
  rb1 = *(const uint4*)(Wb + (size_t)(sr + 32) * K + (k0) + sc8);
#define G1_WRITE(buf)                                \
  *(uint4*)(lA[buf] + sr * LDT + sc8) = ra0;         \
  *(uint4*)(lA[buf] + (sr + 32) * LDT + sc8) = ra1;  \
  *(uint4*)(lB[buf] + sr * LDT + sc8) = rb0;         \
  *(uint4*)(lB[buf] + (sr + 32) * LDT + sc8) = rb1;

  G1_LOAD(0)
  G1_WRITE(0)
  __syncthreads();
  const int nk = K / 64;  // 24
  for (int ti = 0; ti < nk; ++ti) {
    const int cur = ti & 1;
    const bool more = (ti + 1 < nk);
    if (more) { G1_LOAD((ti + 1) * 64) }
#pragma unroll
    for (int kk = 0; kk < 2; ++kk) {
      const int koff = (kk * 4 + kgrp) * 8;
      short8 af0 = *(const short8*)(lA[cur] + (wr * 32 + r16) * LDT + koff);
      short8 af1 = *(const short8*)(lA[cur] + (wr * 32 + 16 + r16) * LDT + koff);
      short8 bf0 = *(const short8*)(lB[cur] + (wc * 32 + r16) * LDT + koff);
      short8 bf1 = *(const short8*)(lB[cur] + (wc * 32 + 16 + r16) * LDT + koff);
      acc[0][0] = __builtin_amdgcn_mfma_f32_16x16x32_bf16(af0, bf0, acc[0][0], 0, 0, 0);
      acc[0][1] = __builtin_amdgcn_mfma_f32_16x16x32_bf16(af0, bf1, acc[0][1], 0, 0, 0);
      acc[1][0] = __builtin_amdgcn_mfma_f32_16x16x32_bf16(af1, bf0, acc[1][0], 0, 0, 0);
      acc[1][1] = __builtin_amdgcn_mfma_f32_16x16x32_bf16(af1, bf1, acc[1][1], 0, 0, 0);
    }
    if (more) { G1_WRITE(cur ^ 1) }
    __syncthreads();
  }

#pragma unroll
  for (int ni = 0; ni < 2; ++ni) {
    const int col = bn * 64 + wc * 32 + ni * 16 + r16;
    const float bv = bias[col];
    float s = 0.f, s2 = 0.f;
#pragma unroll
    for (int mi = 0; mi < 2; ++mi)
#pragma unroll
      for (int rg = 0; rg < 4; ++rg) {
        const int row = bm * 64 + wr * 32 + mi * 16 + kgrp * 4 + rg;
        const float v = acc[mi][ni][rg] + bv;
        y[(size_t)row * N + col] = v;
        s += v; s2 += v * v;
      }
    s = kred(s); s2 = kred(s2);
    if (lane < 16) {
      red[wr][wc * 32 + ni * 16 + r16][0] = s;
      red[wr][wc * 32 + ni * 16 + r16][1] = s2;
    }
  }
  __syncthreads();
  if (tid < 128) {
    const int col = tid >> 1, wh = tid & 1;
    p1[((size_t)bm * DIM + bn * 64 + col) * 2 + wh] = red[0][col][wh] + red[1][col][wh];
  }
}

// ---------------- 3. gemm2: y2 = relu(bn1(y1)) @ w2b^T + b2; + column partials ----------------
// BM=32, BN=32 -> 256 blocks (full chip); 4 waves 2x2, wave tile 16x16; BN1 in A-staging
__global__ __launch_bounds__(256) void gemm2_kernel(
    const float* __restrict__ y1, const u16* __restrict__ W,
    const float* __restrict__ bias, const float* __restrict__ g, const float* __restrict__ be,
    const float* __restrict__ p1, float* __restrict__ y2, float* __restrict__ p2) {
  __shared__ u16 lA[2][32 * LDT];
  __shared__ u16 lB[2][32 * LDT];
  __shared__ float sS[DIM], sH[DIM];
  __shared__ float red[2][32][2];
  const int K = DIM, N = HID;
  const int tid = threadIdx.x, lane = tid & 63, wv = tid >> 6;
  const int wr = wv >> 1, wc = wv & 1;
  const int r16 = lane & 15, kgrp = lane >> 4;
  const int d = blockIdx.x;
  const int g8 = d & 7, j = d >> 3;     // XCD chunk: 4bm x 8bn per XCD
  const int bm = g8 * 4 + (j & 3);      // 0..31
  const int bn = j >> 2;                // 0..7
  const int sr = tid >> 3, sc8 = (tid & 7) * 8;

  for (int c = tid; c < DIM; c += 256) {
    float s = 0.f, s2 = 0.f;
#pragma unroll
    for (int i = 0; i < 16; ++i) {
      float2 pv = *(const float2*)(p1 + ((size_t)i * DIM + c) * 2);
      s += pv.x; s2 += pv.y;
    }
    const float m = s * (1.f / BATCH);
    const float var = s2 * (1.f / BATCH) - m * m;
    const float r = rsqrtf(var + BN_EPS);
    const float scl = r * g[c];
    sS[c] = scl;
    sH[c] = be[c] - m * scl;
  }
  __syncthreads();

  f32x4 acc = (f32x4){0.f, 0.f, 0.f, 0.f};
  const float* Ab = y1 + (size_t)bm * 32 * K;
  const u16* Wb = W + (size_t)bn * 32 * K;

  f32x4 va0, va1;
  uint4 rbq;
#define G2_LOAD(k0)                                          \
  va0 = *(const f32x4*)(Ab + (size_t)sr * K + (k0) + sc8);   \
  va1 = *(const f32x4*)(Ab + (size_t)sr * K + (k0) + sc8 + 4);\
  rbq = *(const uint4*)(Wb + (size_t)sr * K + (k0) + sc8);

  auto pack_write = [&](int buf, int k0) {
    union { ushort us[8]; uint4 q; } pk;
#pragma unroll
    for (int jj = 0; jj < 4; ++jj) {
      pk.us[jj]     = f2bf(fmaxf(0.f, va0[jj] * sS[k0 + sc8 + jj] + sH[k0 + sc8 + jj]));
      pk.us[4 + jj] = f2bf(fmaxf(0.f, va1[jj] * sS[k0 + sc8 + 4 + jj] + sH[k0 + sc8 + 4 + jj]));
    }
    *(uint4*)(lA[buf] + sr * LDT + sc8) = pk.q;
    *(uint4*)(lB[buf] + sr * LDT + sc8) = rbq;
  };

  G2_LOAD(0)
  pack_write(0, 0);
  __syncthreads();
  const int nk = K / 64;  // 12
  for (int ti = 0; ti < nk; ++ti) {
    const int cur = ti & 1;
    const bool more = (ti + 1 < nk);
    if (more) { G2_LOAD((ti + 1) * 64) }
#pragma unroll
    for (int kk = 0; kk < 2; ++kk) {
      const int koff = (kk * 4 + kgrp) * 8;
      short8 af0 = *(const short8*)(lA[cur] + (wr * 16 + r16) * LDT + koff);
      short8 bf0 = *(const short8*)(lB[cur] + (wc * 16 + r16) * LDT + koff);
      acc = __builtin_amdgcn_mfma_f32_16x16x32_bf16(af0, bf0, acc, 0, 0, 0);
    }
    if (more) pack_write(cur ^ 1, (ti + 1) * 64);
    __syncthreads();
  }

  {
    const int col = bn * 32 + wc * 16 + r16;
    const float bv = bias[col];
    float s = 0.f, s2 = 0.f;
#pragma unroll
    for (int rg = 0; rg < 4; ++rg) {
      const int row = bm * 32 + wr * 16 + kgrp * 4 + rg;
      const float v = acc[rg] + bv;
      y2[(size_t)row * N + col] = v;
      s += v; s2 += v * v;
    }
    s = kred(s); s2 = kred(s2);
    if (lane < 16) {
      red[wr][wc * 16 + r16][0] = s;
      red[wr][wc * 16 + r16][1] = s2;
    }
  }
  __syncthreads();
  if (tid < 64) {
    const int col = tid >> 1, wh = tid & 1;
    p2[((size_t)bm * HID + bn * 32 + col) * 2 + wh] = red[0][col][wh] + red[1][col][wh];
  }
}

// ---------------- 4. fc3: out = sigmoid(relu(bn2(y2)) @ w3^T + b3) ----------------
__global__ __launch_bounds__(256) void fc3_kernel(
    const float* __restrict__ y2, const float* __restrict__ p2,
    const float* __restrict__ g, const float* __restrict__ be,
    const float* __restrict__ w3, const float* __restrict__ b3, float* __restrict__ out) {
  __shared__ float sS[HID], sH[HID];
  const int tid = threadIdx.x;
  {
    const int c = tid;
    float s = 0.f, s2 = 0.f;
#pragma unroll
    for (int i = 0; i < 32; ++i) {
      float2 pv = *(const float2*)(p2 + ((size_t)i * HID + c) * 2);
      s += pv.x; s2 += pv.y;
    }
    const float m = s * (1.f / BATCH);
    const float var = s2 * (1.f / BATCH) - m * m;
    const float r = rsqrtf(var + BN_EPS);
    const float scl = r * g[c];
    sS[c] = scl;
    sH[c] = be[c] - m * scl;
  }
  __syncthreads();
  const int row = blockIdx.x * 4 + (tid >> 6);
  const int lane = tid & 63;
  f32x4 xv = *(const f32x4*)(y2 + (size_t)row * HID + lane * 4);
  f32x4 sc = *(const f32x4*)&sS[lane * 4];
  f32x4 sh = *(const f32x4*)&sH[lane * 4];
  f32x4 wv = *(const f32x4*)(w3 + lane * 4);
  float dsum = 0.f;
#pragma unroll
  for (int jj = 0; jj < 4; ++jj) dsum += fmaxf(0.f, xv[jj] * sc[jj] + sh[jj]) * wv[jj];
#pragma unroll
  for (int off = 32; off > 0; off >>= 1) dsum += __shfl_xor(dsum, off);
  if (lane == 0) out[row] = 1.f / (1.f + expf(-(dsum + b3[0])));
}

// ---------------- launch ----------------
extern "C" void kernel_launch(void* const* d_in, const int* in_sizes, int n_in,
                              void* d_out, int out_size, void* d_ws, size_t ws_size,
                              hipStream_t stream) {
  const float* uf   = (const float*)d_in[0];
  const float* hf   = (const float*)d_in[1];
  const int*   ul   = (const int*)d_in[2];
  const int*   hl   = (const int*)d_in[3];
  const float* fc1w = (const float*)d_in[4];
  const float* fc1b = (const float*)d_in[5];
  const float* bn1g = (const float*)d_in[6];
  const float* bn1b = (const float*)d_in[7];
  const float* fc2w = (const float*)d_in[8];
  const float* fc2b = (const float*)d_in[9];
  const float* bn2g = (const float*)d_in[10];
  const float* bn2b = (const float*)d_in[11];
  const float* fc3w = (const float*)d_in[12];
  const float* fc3b = (const float*)d_in[13];
  float* out = (float*)d_out;

  char* ws = (char*)d_ws;
  u16*   xb  = (u16*)  (ws + 0);          // 1024*1536 bf16  (3145728 B)
  u16*   w1b = (u16*)  (ws + 3145728);    // 768*1536 bf16   (2359296 B)
  u16*   w2b = (u16*)  (ws + 5505024);    // 256*768 bf16    (393216 B)
  float* y1  = (float*)(ws + 5898240);    // 1024*768 f32    (3145728 B)
  float* y2  = (float*)(ws + 9043968);    // 1024*256 f32    (1048576 B)
  float* p1  = (float*)(ws + 10092544);   // 16*768*2 f32    (98304 B)
  float* p2  = (float*)(ws + 10190848);   // 32*256*2 f32    (65536 B)

  pool_prep_kernel<<<2048 + PREP_BLK, 192, 0, stream>>>(uf, hf, ul, hl, fc1w, fc2w, xb, w1b, w2b);
  gemm1_kernel<<<192, 256, 0, stream>>>(xb, w1b, fc1b, y1, p1);
  gemm2_kernel<<<256, 256, 0, stream>>>(y1, w2b, fc2b, bn1g, bn1b, p1, y2, p2);
  fc3_kernel<<<256, 256, 0, stream>>>(y2, p2, bn2g, bn2b, fc3w, fc3b, out);
}